// Round 1
// baseline (157.380 us; speedup 1.0000x reference)
//
#include <hip/hip_runtime.h>
#include <hip/hip_bf16.h>

// SupervisedGraphSage forward, restructured via linearity of matmul-over-concat:
//   PQ[i][0:32]  = feat[i] @ W1[:, 0:512].T      (P)
//   PQ[i][32:64] = feat[i] @ W1[:, 512:1024].T   (Q)
//   H1[i] = relu(P[i] + 0.2 * sum_s Q[neigh1[i][s]])          (layer-1 for ALL nodes)
//   comb2[b] = [H1[nodes[b]], 0.2 * sum_s H1[neigh2[b][s]]]
//   out[b] = relu(comb2 @ W2.T) @ Wc.T
//
// N_NODES=100000, N_FEATS=512, HIDDEN=32, N_CLASSES=40, BATCH=16384, S=5

#define NFEAT 512
#define NPQ   64   // 2*HIDDEN outputs of K1
#define HID   32
#define NCLS  40
#define SAMP  5

// ---------------- K1: PQ = feat @ Wr.T  (M x 512) @ (512 x 64) ----------------
// Tile: 128 rows x 64 cols, 256 threads, 8x4 micro-tile, K-chunk 16.
#define K1_TM 128
#define K1_TN 64
#define K1_KC 16

__global__ __launch_bounds__(256) void k1_gemm(
    const float* __restrict__ feat, const float* __restrict__ W1,
    float* __restrict__ PQ, int M) {
  __shared__ __align__(16) float As[K1_KC][K1_TM];
  __shared__ __align__(16) float Bs[K1_KC][K1_TN];

  const int tid  = threadIdx.x;
  const int row0 = blockIdx.x * K1_TM;

  // A loader: 2048 floats/chunk = 256 thr * 8 (two float4)
  const int a_row = tid & 127;
  const int a_k   = (tid >> 7) * 8;            // 0 or 8
  // B loader: 1024 floats/chunk = 256 thr * 4 (one float4)
  const int b_col  = tid & 63;                 // output j in 0..63
  const int b_k    = (tid >> 6) * 4;           // 0,4,8,12
  const int b_wrow = b_col & 31;               // W1 row
  const int b_koff = (b_col >> 5) * NFEAT;     // 0 (P) or 512 (Q)

  // compute mapping: 16 row-groups x 16 col-groups
  const int r0 = (tid & 15) * 8;
  const int c0 = (tid >> 4) * 4;

  float acc[8][4];
#pragma unroll
  for (int i = 0; i < 8; ++i)
#pragma unroll
    for (int j = 0; j < 4; ++j) acc[i][j] = 0.f;

  int ga_row = row0 + a_row;
  if (ga_row >= M) ga_row = M - 1;             // clamp; stores are guarded
  const float* feat_row = feat + (size_t)ga_row * NFEAT;
  const float* w_row    = W1 + b_wrow * (2 * NFEAT) + b_koff;

  // prefetch chunk 0
  float4 a0 = *(const float4*)(feat_row + a_k);
  float4 a1 = *(const float4*)(feat_row + a_k + 4);
  float4 bb = *(const float4*)(w_row + b_k);

  for (int k0 = 0; k0 < NFEAT; k0 += K1_KC) {
    __syncthreads();
    As[a_k + 0][a_row] = a0.x; As[a_k + 1][a_row] = a0.y;
    As[a_k + 2][a_row] = a0.z; As[a_k + 3][a_row] = a0.w;
    As[a_k + 4][a_row] = a1.x; As[a_k + 5][a_row] = a1.y;
    As[a_k + 6][a_row] = a1.z; As[a_k + 7][a_row] = a1.w;
    Bs[b_k + 0][b_col] = bb.x; Bs[b_k + 1][b_col] = bb.y;
    Bs[b_k + 2][b_col] = bb.z; Bs[b_k + 3][b_col] = bb.w;
    __syncthreads();

    const int kn = k0 + K1_KC;
    if (kn < NFEAT) {   // prefetch next chunk while computing this one
      a0 = *(const float4*)(feat_row + kn + a_k);
      a1 = *(const float4*)(feat_row + kn + a_k + 4);
      bb = *(const float4*)(w_row + kn + b_k);
    }

#pragma unroll
    for (int kk = 0; kk < K1_KC; ++kk) {
      float4 av0 = *(const float4*)&As[kk][r0];
      float4 av1 = *(const float4*)&As[kk][r0 + 4];
      float4 bv  = *(const float4*)&Bs[kk][c0];
      float ar[8] = {av0.x, av0.y, av0.z, av0.w, av1.x, av1.y, av1.z, av1.w};
      float br[4] = {bv.x, bv.y, bv.z, bv.w};
#pragma unroll
      for (int i = 0; i < 8; ++i)
#pragma unroll
        for (int j = 0; j < 4; ++j) acc[i][j] += ar[i] * br[j];
    }
  }

#pragma unroll
  for (int i = 0; i < 8; ++i) {
    int row = row0 + r0 + i;
    if (row < M) {
      float4 v;
      v.x = acc[i][0]; v.y = acc[i][1]; v.z = acc[i][2]; v.w = acc[i][3];
      *(float4*)(PQ + (size_t)row * NPQ + c0) = v;
    }
  }
}

// ---------------- K2: H1[i] = relu(P[i] + 0.2 * sum_s Q[neigh1[i][s]]) ----------------
__global__ __launch_bounds__(256) void k2_agg(
    const float* __restrict__ PQ, const int* __restrict__ neigh1,
    float* __restrict__ H1, int M) {
  int gid = blockIdx.x * 256 + threadIdx.x;
  if (gid >= M * 8) return;
  int i = gid >> 3;
  int q = gid & 7;                 // which float4 of the 32 outputs

  const float4 p = *(const float4*)(PQ + (size_t)i * NPQ + q * 4);
  float ax = 0.f, ay = 0.f, az = 0.f, aw = 0.f;
#pragma unroll
  for (int s = 0; s < SAMP; ++s) {
    int n = neigh1[i * SAMP + s];
    const float4 v = *(const float4*)(PQ + (size_t)n * NPQ + HID + q * 4);
    ax += v.x; ay += v.y; az += v.z; aw += v.w;
  }
  float4 r;
  r.x = fmaxf(p.x + 0.2f * ax, 0.f);
  r.y = fmaxf(p.y + 0.2f * ay, 0.f);
  r.z = fmaxf(p.z + 0.2f * az, 0.f);
  r.w = fmaxf(p.w + 0.2f * aw, 0.f);
  *(float4*)(H1 + (size_t)i * HID + q * 4) = r;
}

// ---------------- K3: layer-2 + classifier, one thread per batch row ----------------
__global__ __launch_bounds__(64) void k3_layer2(
    const float* __restrict__ H1, const float* __restrict__ W2,
    const float* __restrict__ Wc, const int* __restrict__ nodes,
    const int* __restrict__ neigh2, float* __restrict__ out, int B) {
  int b = blockIdx.x * 64 + threadIdx.x;
  if (b >= B) return;

  float comb[64];
  {
    const float* hs = H1 + (size_t)nodes[b] * HID;
#pragma unroll
    for (int q = 0; q < 8; ++q) {
      float4 v = *(const float4*)(hs + q * 4);
      comb[q * 4 + 0] = v.x; comb[q * 4 + 1] = v.y;
      comb[q * 4 + 2] = v.z; comb[q * 4 + 3] = v.w;
    }
  }
  {
    float na[HID];
#pragma unroll
    for (int h = 0; h < HID; ++h) na[h] = 0.f;
#pragma unroll
    for (int s = 0; s < SAMP; ++s) {
      const float* hn = H1 + (size_t)neigh2[b * SAMP + s] * HID;
#pragma unroll
      for (int q = 0; q < 8; ++q) {
        float4 v = *(const float4*)(hn + q * 4);
        na[q * 4 + 0] += v.x; na[q * 4 + 1] += v.y;
        na[q * 4 + 2] += v.z; na[q * 4 + 3] += v.w;
      }
    }
#pragma unroll
    for (int h = 0; h < HID; ++h) comb[HID + h] = 0.2f * na[h];
  }

  float h2[HID];
#pragma unroll 4
  for (int h = 0; h < HID; ++h) {
    float a = 0.f;
#pragma unroll
    for (int k = 0; k < 2 * HID; ++k) a += comb[k] * W2[h * 2 * HID + k];
    h2[h] = a > 0.f ? a : 0.f;
  }

  float* ob = out + (size_t)b * NCLS;
#pragma unroll 4
  for (int c = 0; c < NCLS; ++c) {
    float a = 0.f;
#pragma unroll
    for (int k = 0; k < HID; ++k) a += h2[k] * Wc[c * HID + k];
    ob[c] = a;
  }
}

extern "C" void kernel_launch(void* const* d_in, const int* in_sizes, int n_in,
                              void* d_out, int out_size, void* d_ws, size_t ws_size,
                              hipStream_t stream) {
  const float* feat   = (const float*)d_in[0];
  const float* W1     = (const float*)d_in[1];
  const float* W2     = (const float*)d_in[2];
  const float* Wc     = (const float*)d_in[3];
  const int*   nodes  = (const int*)d_in[4];
  const int*   neigh1 = (const int*)d_in[5];
  const int*   neigh2 = (const int*)d_in[6];
  float* out = (float*)d_out;

  const int M = in_sizes[0] / NFEAT;   // 100000 nodes
  const int B = in_sizes[4];           // 16384 batch

  // workspace layout: PQ [M][64] f32, then H1 [M][32] f32  (~38.4 MB total)
  size_t need = (size_t)M * NPQ * sizeof(float) + (size_t)M * HID * sizeof(float);
  if (ws_size < need) return;  // fail loudly (output stays poisoned)

  float* PQ = (float*)d_ws;
  float* H1 = PQ + (size_t)M * NPQ;

  k1_gemm<<<(M + K1_TM - 1) / K1_TM, 256, 0, stream>>>(feat, W1, PQ, M);
  k2_agg<<<(M * 8 + 255) / 256, 256, 0, stream>>>(PQ, neigh1, H1, M);
  k3_layer2<<<(B + 63) / 64, 64, 0, stream>>>(H1, W2, Wc, nodes, neigh2, out, B);
}

// Round 2
// 111.560 us; speedup vs baseline: 1.4107x; 1.4107x over previous
//
#include <hip/hip_runtime.h>
#include <hip/hip_bf16.h>

// SupervisedGraphSage forward via linearity of matmul-over-concat:
//   PQ[i][0:32]  = feat[i] @ W1[:, 0:512].T      (P)
//   PQ[i][32:64] = feat[i] @ W1[:, 512:1024].T   (Q)
//   H1[i] = relu(P[i] + 0.2 * sum_s Q[neigh1[i][s]])
//   comb2[b] = [H1[nodes[b]], 0.2 * sum_s H1[neigh2[b][s]]]
//   out[b] = relu(comb2 @ W2.T) @ Wc.T
//
// K1 now uses v_mfma_f32_16x16x16_f16 (classic CDNA fragment layout):
//   A: lane l holds row l&15, k = 4*(l>>4)+j   (j=0..3)
//   B: lane l holds col l&15, k = 4*(l>>4)+j
//   C: lane l reg r -> row 4*(l>>4)+r, col l&15
// feat is converted f32->f16 in-register; W1 pre-packed to f16 B-fragments by k0.

#define NFEAT 512
#define NPQ   64
#define HID   32
#define NCLS  40
#define SAMP  5
#define KSTEPS (NFEAT / 16)   // 32

typedef float   f32x4 __attribute__((ext_vector_type(4)));
typedef _Float16 f16x4 __attribute__((ext_vector_type(4)));

// ---------------- k0: pack W1 (f32 [32][1024]) into f16 B-fragments ----------------
// Bfrag index: ((kstep*4 + tile)*64 + lane) * 4 + j
//   element = B[k][n], k = kstep*16 + 4*(lane>>4) + j, n = tile*16 + (lane&15)
//   B[k][n] = W1[n&31][(n>>5)*512 + k]
__global__ __launch_bounds__(256) void k0_bfrag(const float* __restrict__ W1,
                                                _Float16* __restrict__ Bfrag) {
  int idx = blockIdx.x * 256 + threadIdx.x;
  if (idx >= KSTEPS * 4 * 64) return;
  int lane = idx & 63;
  int tile = (idx >> 6) & 3;
  int kstep = idx >> 8;
  int n = tile * 16 + (lane & 15);
  int kbase = kstep * 16 + ((lane >> 4) << 2);
  const float* src = W1 + (size_t)(n & 31) * (2 * NFEAT) + (n >> 5) * NFEAT + kbase;
  _Float16* dst = Bfrag + (size_t)idx * 4;
#pragma unroll
  for (int j = 0; j < 4; ++j) dst[j] = (_Float16)src[j];
}

// ---------------- K1: PQ = feat @ Wr.T via MFMA, memory-bound streaming ----------------
// 256 threads = 4 waves; each wave computes 16 rows x 64 cols. No LDS.
__global__ __launch_bounds__(256) void k1_mfma(
    const float* __restrict__ feat, const _Float16* __restrict__ Bfrag,
    float* __restrict__ PQ, int M) {
  const int wave = threadIdx.x >> 6;
  const int lane = threadIdx.x & 63;
  const int rowbase = blockIdx.x * 64 + wave * 16;

  int arow = rowbase + (lane & 15);
  if (arow >= M) arow = M - 1;                      // clamp; stores guarded
  const float* ap = feat + (size_t)arow * NFEAT + ((lane >> 4) << 2);
  const f16x4* bp = (const f16x4*)Bfrag + lane;

  f32x4 acc0 = {0.f, 0.f, 0.f, 0.f};
  f32x4 acc1 = {0.f, 0.f, 0.f, 0.f};
  f32x4 acc2 = {0.f, 0.f, 0.f, 0.f};
  f32x4 acc3 = {0.f, 0.f, 0.f, 0.f};

#pragma unroll 8
  for (int ks = 0; ks < KSTEPS; ++ks) {
    float4 av = *(const float4*)(ap + ks * 16);
    f16x4 a;
    a[0] = (_Float16)av.x; a[1] = (_Float16)av.y;
    a[2] = (_Float16)av.z; a[3] = (_Float16)av.w;
    const f16x4* bb = bp + ks * 256;
    f16x4 b0 = bb[0];
    f16x4 b1 = bb[64];
    f16x4 b2 = bb[128];
    f16x4 b3 = bb[192];
    acc0 = __builtin_amdgcn_mfma_f32_16x16x16f16(a, b0, acc0, 0, 0, 0);
    acc1 = __builtin_amdgcn_mfma_f32_16x16x16f16(a, b1, acc1, 0, 0, 0);
    acc2 = __builtin_amdgcn_mfma_f32_16x16x16f16(a, b2, acc2, 0, 0, 0);
    acc3 = __builtin_amdgcn_mfma_f32_16x16x16f16(a, b3, acc3, 0, 0, 0);
  }

  // C layout: row = rowbase + 4*(lane>>4) + reg, col = tile*16 + (lane&15)
  const int rb = rowbase + ((lane >> 4) << 2);
  const int cl = lane & 15;
#pragma unroll
  for (int r = 0; r < 4; ++r) {
    int row = rb + r;
    if (row < M) {
      float* orow = PQ + (size_t)row * NPQ + cl;
      orow[0]  = acc0[r];
      orow[16] = acc1[r];
      orow[32] = acc2[r];
      orow[48] = acc3[r];
    }
  }
}

// ---------------- K2: H1[i] = relu(P[i] + 0.2 * sum_s Q[neigh1[i][s]]) ----------------
__global__ __launch_bounds__(256) void k2_agg(
    const float* __restrict__ PQ, const int* __restrict__ neigh1,
    float* __restrict__ H1, int M) {
  int gid = blockIdx.x * 256 + threadIdx.x;
  if (gid >= M * 8) return;
  int i = gid >> 3;
  int q = gid & 7;

  const float4 p = *(const float4*)(PQ + (size_t)i * NPQ + q * 4);
  float ax = 0.f, ay = 0.f, az = 0.f, aw = 0.f;
#pragma unroll
  for (int s = 0; s < SAMP; ++s) {
    int n = neigh1[i * SAMP + s];
    const float4 v = *(const float4*)(PQ + (size_t)n * NPQ + HID + q * 4);
    ax += v.x; ay += v.y; az += v.z; aw += v.w;
  }
  float4 r;
  r.x = fmaxf(p.x + 0.2f * ax, 0.f);
  r.y = fmaxf(p.y + 0.2f * ay, 0.f);
  r.z = fmaxf(p.z + 0.2f * az, 0.f);
  r.w = fmaxf(p.w + 0.2f * aw, 0.f);
  *(float4*)(H1 + (size_t)i * HID + q * 4) = r;
}

// ---------------- K3: layer-2 + classifier, one thread per batch row ----------------
__global__ __launch_bounds__(64) void k3_layer2(
    const float* __restrict__ H1, const float* __restrict__ W2,
    const float* __restrict__ Wc, const int* __restrict__ nodes,
    const int* __restrict__ neigh2, float* __restrict__ out, int B) {
  int b = blockIdx.x * 64 + threadIdx.x;
  if (b >= B) return;

  float comb[64];
  {
    const float* hs = H1 + (size_t)nodes[b] * HID;
#pragma unroll
    for (int q = 0; q < 8; ++q) {
      float4 v = *(const float4*)(hs + q * 4);
      comb[q * 4 + 0] = v.x; comb[q * 4 + 1] = v.y;
      comb[q * 4 + 2] = v.z; comb[q * 4 + 3] = v.w;
    }
  }
  {
    float na[HID];
#pragma unroll
    for (int h = 0; h < HID; ++h) na[h] = 0.f;
#pragma unroll
    for (int s = 0; s < SAMP; ++s) {
      const float* hn = H1 + (size_t)neigh2[b * SAMP + s] * HID;
#pragma unroll
      for (int q = 0; q < 8; ++q) {
        float4 v = *(const float4*)(hn + q * 4);
        na[q * 4 + 0] += v.x; na[q * 4 + 1] += v.y;
        na[q * 4 + 2] += v.z; na[q * 4 + 3] += v.w;
      }
    }
#pragma unroll
    for (int h = 0; h < HID; ++h) comb[HID + h] = 0.2f * na[h];
  }

  float h2[HID];
#pragma unroll 4
  for (int h = 0; h < HID; ++h) {
    float a = 0.f;
#pragma unroll
    for (int k = 0; k < 2 * HID; ++k) a += comb[k] * W2[h * 2 * HID + k];
    h2[h] = a > 0.f ? a : 0.f;
  }

  float* ob = out + (size_t)b * NCLS;
#pragma unroll 4
  for (int c = 0; c < NCLS; ++c) {
    float a = 0.f;
#pragma unroll
    for (int k = 0; k < HID; ++k) a += h2[k] * Wc[c * HID + k];
    ob[c] = a;
  }
}

extern "C" void kernel_launch(void* const* d_in, const int* in_sizes, int n_in,
                              void* d_out, int out_size, void* d_ws, size_t ws_size,
                              hipStream_t stream) {
  const float* feat   = (const float*)d_in[0];
  const float* W1     = (const float*)d_in[1];
  const float* W2     = (const float*)d_in[2];
  const float* Wc     = (const float*)d_in[3];
  const int*   nodes  = (const int*)d_in[4];
  const int*   neigh1 = (const int*)d_in[5];
  const int*   neigh2 = (const int*)d_in[6];
  float* out = (float*)d_out;

  const int M = in_sizes[0] / NFEAT;   // 100000 nodes
  const int B = in_sizes[4];           // 16384 batch

  // workspace: Bfrag f16 [32*4*64*4] (64 KB), PQ f32 [M][64], H1 f32 [M][32]
  size_t bfrag_elems = (size_t)KSTEPS * 4 * 64 * 4;
  size_t need = bfrag_elems * sizeof(_Float16)
              + (size_t)M * NPQ * sizeof(float)
              + (size_t)M * HID * sizeof(float);
  if (ws_size < need) return;  // fail loudly (output stays poisoned)

  _Float16* Bfrag = (_Float16*)d_ws;
  float* PQ = (float*)(Bfrag + bfrag_elems);
  float* H1 = PQ + (size_t)M * NPQ;

  k0_bfrag<<<(KSTEPS * 4 * 64 + 255) / 256, 256, 0, stream>>>(W1, Bfrag);
  k1_mfma<<<(M + 63) / 64, 256, 0, stream>>>(feat, Bfrag, PQ, M);
  k2_agg<<<(M * 8 + 255) / 256, 256, 0, stream>>>(PQ, neigh1, H1, M);
  k3_layer2<<<(B + 63) / 64, 64, 0, stream>>>(H1, W2, Wc, nodes, neigh2, out, B);
}

// Round 3
// 99.959 us; speedup vs baseline: 1.5744x; 1.1161x over previous
//
#include <hip/hip_runtime.h>
#include <hip/hip_bf16.h>

// SupervisedGraphSage forward via linearity of matmul-over-concat:
//   PQ[i][0:32]  = feat[i] @ W1[:, 0:512].T      (P)
//   PQ[i][32:64] = feat[i] @ W1[:, 512:1024].T   (Q)
//   H1[i] = relu(P[i] + 0.2 * sum_s Q[neigh1[i][s]])
//   comb2[b] = [H1[nodes[b]], 0.2 * sum_s H1[neigh2[b][s]]]
//   out[b] = relu(comb2 @ W2.T) @ Wc.T
//
// Intermediates PQ/H1 stored f16 (f32 accumulate everywhere; threshold 3.3e-2).
// K1: v_mfma_f32_16x16x16_f16, classic CDNA layout:
//   A: lane l holds row l&15, k = 4*(l>>4)+j ; B: col l&15, same k
//   C: lane l reg r -> row 4*(l>>4)+r, col l&15

#define NFEAT 512
#define NPQ   64
#define HID   32
#define NCLS  40
#define SAMP  5
#define KSTEPS (NFEAT / 16)   // 32

typedef float    f32x4 __attribute__((ext_vector_type(4)));
typedef _Float16 f16x4 __attribute__((ext_vector_type(4)));
typedef _Float16 f16x8 __attribute__((ext_vector_type(8)));

// ---------------- k0: pack W1 (f32 [32][1024]) into f16 B-fragments ----------------
// Layout: Bfrag[((kstep*64 + lane)*4 + tile)*4 + j]  -> lane's 4 tile-frags contiguous (32B)
//   element B[k][n]: k = kstep*16 + 4*(lane>>4)+j, n = tile*16 + (lane&15)
//   B[k][n] = W1[n&31][(n>>5)*512 + k]
__global__ __launch_bounds__(256) void k0_bfrag(const float* __restrict__ W1,
                                                _Float16* __restrict__ Bfrag) {
  int idx = blockIdx.x * 256 + threadIdx.x;   // (kstep*64 + lane)*4 + tile
  if (idx >= KSTEPS * 64 * 4) return;
  int tile  = idx & 3;
  int lane  = (idx >> 2) & 63;
  int kstep = idx >> 8;
  int n = tile * 16 + (lane & 15);
  int kbase = kstep * 16 + ((lane >> 4) << 2);
  const float* src = W1 + (size_t)(n & 31) * (2 * NFEAT) + (n >> 5) * NFEAT + kbase;
  _Float16* dst = Bfrag + (size_t)idx * 4;
#pragma unroll
  for (int j = 0; j < 4; ++j) dst[j] = (_Float16)src[j];
}

// ---------------- K1: PQ(f16) = feat @ Wr.T via MFMA, streaming ----------------
__global__ __launch_bounds__(256) void k1_mfma(
    const float* __restrict__ feat, const _Float16* __restrict__ Bfrag,
    _Float16* __restrict__ PQ, int M) {
  const int wave = threadIdx.x >> 6;
  const int lane = threadIdx.x & 63;
  const int rowbase = blockIdx.x * 64 + wave * 16;

  int arow = rowbase + (lane & 15);
  if (arow >= M) arow = M - 1;                      // clamp; stores guarded
  const float* ap = feat + (size_t)arow * NFEAT + ((lane >> 4) << 2);
  const _Float16* bp = Bfrag + (size_t)lane * 16;

  f32x4 acc0 = {0.f, 0.f, 0.f, 0.f};
  f32x4 acc1 = {0.f, 0.f, 0.f, 0.f};
  f32x4 acc2 = {0.f, 0.f, 0.f, 0.f};
  f32x4 acc3 = {0.f, 0.f, 0.f, 0.f};

#pragma unroll 8
  for (int ks = 0; ks < KSTEPS; ++ks) {
    float4 av = *(const float4*)(ap + ks * 16);
    f16x4 a;
    a[0] = (_Float16)av.x; a[1] = (_Float16)av.y;
    a[2] = (_Float16)av.z; a[3] = (_Float16)av.w;
    const _Float16* bb = bp + (size_t)ks * 1024;   // (ks*64+lane)*16
    f16x8 b01 = *(const f16x8*)bb;
    f16x8 b23 = *(const f16x8*)(bb + 8);
    f16x4 b0 = __builtin_shufflevector(b01, b01, 0, 1, 2, 3);
    f16x4 b1 = __builtin_shufflevector(b01, b01, 4, 5, 6, 7);
    f16x4 b2 = __builtin_shufflevector(b23, b23, 0, 1, 2, 3);
    f16x4 b3 = __builtin_shufflevector(b23, b23, 4, 5, 6, 7);
    acc0 = __builtin_amdgcn_mfma_f32_16x16x16f16(a, b0, acc0, 0, 0, 0);
    acc1 = __builtin_amdgcn_mfma_f32_16x16x16f16(a, b1, acc1, 0, 0, 0);
    acc2 = __builtin_amdgcn_mfma_f32_16x16x16f16(a, b2, acc2, 0, 0, 0);
    acc3 = __builtin_amdgcn_mfma_f32_16x16x16f16(a, b3, acc3, 0, 0, 0);
  }

  // C layout: row = rowbase + 4*(lane>>4) + reg, col = tile*16 + (lane&15)
  const int rb = rowbase + ((lane >> 4) << 2);
  const int cl = lane & 15;
#pragma unroll
  for (int r = 0; r < 4; ++r) {
    int row = rb + r;
    if (row < M) {
      _Float16* orow = PQ + (size_t)row * NPQ + cl;
      orow[0]  = (_Float16)acc0[r];
      orow[16] = (_Float16)acc1[r];
      orow[32] = (_Float16)acc2[r];
      orow[48] = (_Float16)acc3[r];
    }
  }
}

// ---------------- K2: H1[i] = relu(P[i] + 0.2 * sum_s Q[neigh1[i][s]]) ----------------
// 4 threads per node, 8 f16 lanes each (16B loads/stores).
__global__ __launch_bounds__(256) void k2_agg(
    const _Float16* __restrict__ PQ, const int* __restrict__ neigh1,
    _Float16* __restrict__ H1, int M) {
  int gid = blockIdx.x * 256 + threadIdx.x;
  if (gid >= M * 4) return;
  int i = gid >> 2;
  int q = gid & 3;                 // which f16x8 of the 32 outputs

  f16x8 p = *(const f16x8*)(PQ + (size_t)i * NPQ + q * 8);
  float acc[8];
#pragma unroll
  for (int j = 0; j < 8; ++j) acc[j] = 0.f;
#pragma unroll
  for (int s = 0; s < SAMP; ++s) {
    int n = neigh1[i * SAMP + s];
    f16x8 v = *(const f16x8*)(PQ + (size_t)n * NPQ + HID + q * 8);
#pragma unroll
    for (int j = 0; j < 8; ++j) acc[j] += (float)v[j];
  }
  f16x8 r;
#pragma unroll
  for (int j = 0; j < 8; ++j)
    r[j] = (_Float16)fmaxf((float)p[j] + 0.2f * acc[j], 0.f);
  *(f16x8*)(H1 + (size_t)i * HID + q * 8) = r;
}

// ---------------- K3: layer-2 + classifier, one thread per batch row ----------------
__global__ __launch_bounds__(64) void k3_layer2(
    const _Float16* __restrict__ H1, const float* __restrict__ W2,
    const float* __restrict__ Wc, const int* __restrict__ nodes,
    const int* __restrict__ neigh2, float* __restrict__ out, int B) {
  int b = blockIdx.x * 64 + threadIdx.x;
  if (b >= B) return;

  float comb[64];
  {
    const _Float16* hs = H1 + (size_t)nodes[b] * HID;
#pragma unroll
    for (int q = 0; q < 4; ++q) {
      f16x8 v = *(const f16x8*)(hs + q * 8);
#pragma unroll
      for (int j = 0; j < 8; ++j) comb[q * 8 + j] = (float)v[j];
    }
  }
  {
    float na[HID];
#pragma unroll
    for (int h = 0; h < HID; ++h) na[h] = 0.f;
#pragma unroll
    for (int s = 0; s < SAMP; ++s) {
      const _Float16* hn = H1 + (size_t)neigh2[b * SAMP + s] * HID;
#pragma unroll
      for (int q = 0; q < 4; ++q) {
        f16x8 v = *(const f16x8*)(hn + q * 8);
#pragma unroll
        for (int j = 0; j < 8; ++j) na[q * 8 + j] += (float)v[j];
      }
    }
#pragma unroll
    for (int h = 0; h < HID; ++h) comb[HID + h] = 0.2f * na[h];
  }

  float h2[HID];
#pragma unroll 4
  for (int h = 0; h < HID; ++h) {
    float a = 0.f;
#pragma unroll
    for (int k = 0; k < 2 * HID; ++k) a += comb[k] * W2[h * 2 * HID + k];
    h2[h] = a > 0.f ? a : 0.f;
  }

  float* ob = out + (size_t)b * NCLS;
#pragma unroll 4
  for (int c = 0; c < NCLS; ++c) {
    float a = 0.f;
#pragma unroll
    for (int k = 0; k < HID; ++k) a += h2[k] * Wc[c * HID + k];
    ob[c] = a;
  }
}

extern "C" void kernel_launch(void* const* d_in, const int* in_sizes, int n_in,
                              void* d_out, int out_size, void* d_ws, size_t ws_size,
                              hipStream_t stream) {
  const float* feat   = (const float*)d_in[0];
  const float* W1     = (const float*)d_in[1];
  const float* W2     = (const float*)d_in[2];
  const float* Wc     = (const float*)d_in[3];
  const int*   nodes  = (const int*)d_in[4];
  const int*   neigh1 = (const int*)d_in[5];
  const int*   neigh2 = (const int*)d_in[6];
  float* out = (float*)d_out;

  const int M = in_sizes[0] / NFEAT;   // 100000 nodes
  const int B = in_sizes[4];           // 16384 batch

  // workspace: Bfrag f16 [32*64*4*4] (64 KB), PQ f16 [M][64], H1 f16 [M][32]
  size_t bfrag_elems = (size_t)KSTEPS * 64 * 4 * 4;
  size_t need = (bfrag_elems + (size_t)M * NPQ + (size_t)M * HID) * sizeof(_Float16);
  if (ws_size < need) return;  // fail loudly (output stays poisoned)

  _Float16* Bfrag = (_Float16*)d_ws;
  _Float16* PQ = Bfrag + bfrag_elems;
  _Float16* H1 = PQ + (size_t)M * NPQ;

  k0_bfrag<<<(KSTEPS * 64 * 4 + 255) / 256, 256, 0, stream>>>(W1, Bfrag);
  k1_mfma<<<(M + 63) / 64, 256, 0, stream>>>(feat, Bfrag, PQ, M);
  k2_agg<<<(M * 4 + 255) / 256, 256, 0, stream>>>(PQ, neigh1, H1, M);
  k3_layer2<<<(B + 63) / 64, 64, 0, stream>>>(H1, W2, Wc, nodes, neigh2, out, B);
}

// Round 4
// 98.729 us; speedup vs baseline: 1.5941x; 1.0125x over previous
//
#include <hip/hip_runtime.h>
#include <hip/hip_bf16.h>

// SupervisedGraphSage forward via linearity of matmul-over-concat:
//   PQ[i][0:32]  = feat[i] @ W1[:, 0:512].T      (P)
//   PQ[i][32:64] = feat[i] @ W1[:, 512:1024].T   (Q)
//   H1[i] = relu(P[i] + 0.2 * sum_s Q[neigh1[i][s]])
//   comb2[b] = [H1[nodes[b]], 0.2 * sum_s H1[neigh2[b][s]]]
//   out[b] = relu(comb2 @ W2.T) @ Wc.T
//
// Intermediates PQ/H1 stored f16 (f32 accumulate; threshold 3.3e-2).
// K1: v_mfma_f32_16x16x16_f16, classic CDNA layout (verified R1/R2):
//   A: lane l holds row l&15, k = 4*(l>>4)+j ; B: col l&15, same k
//   C: lane l reg r -> row 4*(l>>4)+r, col l&15
// R3->R4: k1 widened to 32 rows/wave (128-row blocks, halves Bfrag traffic,
// 8 MFMA : 3 VMEM) + LDS-transposed coalesced f16 stores (was 16x 2B scatter).

#define NFEAT 512
#define NPQ   64
#define HID   32
#define NCLS  40
#define SAMP  5
#define KSTEPS (NFEAT / 16)   // 32

typedef float    f32x4 __attribute__((ext_vector_type(4)));
typedef _Float16 f16x4 __attribute__((ext_vector_type(4)));
typedef _Float16 f16x8 __attribute__((ext_vector_type(8)));

// ---------------- k0: pack W1 (f32 [32][1024]) into f16 B-fragments ----------------
// Layout: Bfrag[((kstep*64 + lane)*4 + tile)*4 + j]  -> lane's 4 tile-frags contiguous
//   element B[k][n]: k = kstep*16 + 4*(lane>>4)+j, n = tile*16 + (lane&15)
//   B[k][n] = W1[n&31][(n>>5)*512 + k]
__global__ __launch_bounds__(256) void k0_bfrag(const float* __restrict__ W1,
                                                _Float16* __restrict__ Bfrag) {
  int idx = blockIdx.x * 256 + threadIdx.x;   // (kstep*64 + lane)*4 + tile
  if (idx >= KSTEPS * 64 * 4) return;
  int tile  = idx & 3;
  int lane  = (idx >> 2) & 63;
  int kstep = idx >> 8;
  int n = tile * 16 + (lane & 15);
  int kbase = kstep * 16 + ((lane >> 4) << 2);
  const float* src = W1 + (size_t)(n & 31) * (2 * NFEAT) + (n >> 5) * NFEAT + kbase;
  _Float16* dst = Bfrag + (size_t)idx * 4;
#pragma unroll
  for (int j = 0; j < 4; ++j) dst[j] = (_Float16)src[j];
}

// ---------------- K1: PQ(f16) = feat @ Wr.T via MFMA ----------------
// 256 threads = 4 waves; each wave computes 32 rows x 64 cols. Block = 128 rows.
__global__ __launch_bounds__(256) void k1_mfma(
    const float* __restrict__ feat, const _Float16* __restrict__ Bfrag,
    _Float16* __restrict__ PQ, int M) {
  __shared__ _Float16 sC[128][64];   // 16 KB staging for coalesced stores

  const int tid  = threadIdx.x;
  const int wave = tid >> 6;
  const int lane = tid & 63;
  const int g    = lane >> 4;        // k-group 0..3
  const int r    = lane & 15;        // A row within 16-tile / C col within tile
  const int blockRow = blockIdx.x * 128;
  const int rowbase  = blockRow + wave * 32;

  int arow0 = rowbase + r;
  int arow1 = rowbase + 16 + r;
  if (arow0 >= M) arow0 = M - 1;     // clamp; stores guarded
  if (arow1 >= M) arow1 = M - 1;
  const float* ap0 = feat + (size_t)arow0 * NFEAT + (g << 2);
  const float* ap1 = feat + (size_t)arow1 * NFEAT + (g << 2);
  const _Float16* bp = Bfrag + (size_t)lane * 16;

  f32x4 acc00 = {0.f,0.f,0.f,0.f}, acc01 = {0.f,0.f,0.f,0.f};
  f32x4 acc02 = {0.f,0.f,0.f,0.f}, acc03 = {0.f,0.f,0.f,0.f};
  f32x4 acc10 = {0.f,0.f,0.f,0.f}, acc11 = {0.f,0.f,0.f,0.f};
  f32x4 acc12 = {0.f,0.f,0.f,0.f}, acc13 = {0.f,0.f,0.f,0.f};

#pragma unroll 4
  for (int ks = 0; ks < KSTEPS; ++ks) {
    float4 av0 = *(const float4*)(ap0 + ks * 16);
    float4 av1 = *(const float4*)(ap1 + ks * 16);
    f16x4 a0, a1;
    a0[0] = (_Float16)av0.x; a0[1] = (_Float16)av0.y;
    a0[2] = (_Float16)av0.z; a0[3] = (_Float16)av0.w;
    a1[0] = (_Float16)av1.x; a1[1] = (_Float16)av1.y;
    a1[2] = (_Float16)av1.z; a1[3] = (_Float16)av1.w;
    const _Float16* bb = bp + (size_t)ks * 1024;   // (ks*64+lane)*16
    f16x8 b01 = *(const f16x8*)bb;
    f16x8 b23 = *(const f16x8*)(bb + 8);
    f16x4 b0 = __builtin_shufflevector(b01, b01, 0, 1, 2, 3);
    f16x4 b1 = __builtin_shufflevector(b01, b01, 4, 5, 6, 7);
    f16x4 b2 = __builtin_shufflevector(b23, b23, 0, 1, 2, 3);
    f16x4 b3 = __builtin_shufflevector(b23, b23, 4, 5, 6, 7);
    acc00 = __builtin_amdgcn_mfma_f32_16x16x16f16(a0, b0, acc00, 0, 0, 0);
    acc01 = __builtin_amdgcn_mfma_f32_16x16x16f16(a0, b1, acc01, 0, 0, 0);
    acc02 = __builtin_amdgcn_mfma_f32_16x16x16f16(a0, b2, acc02, 0, 0, 0);
    acc03 = __builtin_amdgcn_mfma_f32_16x16x16f16(a0, b3, acc03, 0, 0, 0);
    acc10 = __builtin_amdgcn_mfma_f32_16x16x16f16(a1, b0, acc10, 0, 0, 0);
    acc11 = __builtin_amdgcn_mfma_f32_16x16x16f16(a1, b1, acc11, 0, 0, 0);
    acc12 = __builtin_amdgcn_mfma_f32_16x16x16f16(a1, b2, acc12, 0, 0, 0);
    acc13 = __builtin_amdgcn_mfma_f32_16x16x16f16(a1, b3, acc13, 0, 0, 0);
  }

  // C layout per tile: row = 4g + reg (+ rt*16), col = t*16 + r.
  const int lr0 = wave * 32 + 4 * g;        // local row base, rt=0
#pragma unroll
  for (int rg = 0; rg < 4; ++rg) {
    sC[lr0 + rg     ][r     ] = (_Float16)acc00[rg];
    sC[lr0 + rg     ][r + 16] = (_Float16)acc01[rg];
    sC[lr0 + rg     ][r + 32] = (_Float16)acc02[rg];
    sC[lr0 + rg     ][r + 48] = (_Float16)acc03[rg];
    sC[lr0 + rg + 16][r     ] = (_Float16)acc10[rg];
    sC[lr0 + rg + 16][r + 16] = (_Float16)acc11[rg];
    sC[lr0 + rg + 16][r + 32] = (_Float16)acc12[rg];
    sC[lr0 + rg + 16][r + 48] = (_Float16)acc13[rg];
  }
  __syncthreads();

  // coalesced store: thread t -> row t>>1, 32-col half t&1 (64 B per thread)
  const int srow = tid >> 1;
  const int half = (tid & 1) * 32;
  const int grow = blockRow + srow;
  if (grow < M) {
    _Float16* dst = PQ + (size_t)grow * NPQ + half;
    const _Float16* src = &sC[srow][half];
#pragma unroll
    for (int i = 0; i < 4; ++i)
      *(f16x8*)(dst + i * 8) = *(const f16x8*)(src + i * 8);
  }
}

// ---------------- K2: H1[i] = relu(P[i] + 0.2 * sum_s Q[neigh1[i][s]]) ----------------
// 4 threads per node, 8 f16 lanes each (16B loads/stores).
__global__ __launch_bounds__(256) void k2_agg(
    const _Float16* __restrict__ PQ, const int* __restrict__ neigh1,
    _Float16* __restrict__ H1, int M) {
  int gid = blockIdx.x * 256 + threadIdx.x;
  if (gid >= M * 4) return;
  int i = gid >> 2;
  int q = gid & 3;                 // which f16x8 of the 32 outputs

  f16x8 p = *(const f16x8*)(PQ + (size_t)i * NPQ + q * 8);
  float acc[8];
#pragma unroll
  for (int j = 0; j < 8; ++j) acc[j] = 0.f;
#pragma unroll
  for (int s = 0; s < SAMP; ++s) {
    int n = neigh1[i * SAMP + s];
    f16x8 v = *(const f16x8*)(PQ + (size_t)n * NPQ + HID + q * 8);
#pragma unroll
    for (int j = 0; j < 8; ++j) acc[j] += (float)v[j];
  }
  f16x8 rr;
#pragma unroll
  for (int j = 0; j < 8; ++j)
    rr[j] = (_Float16)fmaxf((float)p[j] + 0.2f * acc[j], 0.f);
  *(f16x8*)(H1 + (size_t)i * HID + q * 8) = rr;
}

// ---------------- K3: layer-2 + classifier, one thread per batch row ----------------
__global__ __launch_bounds__(64) void k3_layer2(
    const _Float16* __restrict__ H1, const float* __restrict__ W2,
    const float* __restrict__ Wc, const int* __restrict__ nodes,
    const int* __restrict__ neigh2, float* __restrict__ out, int B) {
  int b = blockIdx.x * 64 + threadIdx.x;
  if (b >= B) return;

  float comb[64];
  {
    const _Float16* hs = H1 + (size_t)nodes[b] * HID;
#pragma unroll
    for (int q = 0; q < 4; ++q) {
      f16x8 v = *(const f16x8*)(hs + q * 8);
#pragma unroll
      for (int j = 0; j < 8; ++j) comb[q * 8 + j] = (float)v[j];
    }
  }
  {
    float na[HID];
#pragma unroll
    for (int h = 0; h < HID; ++h) na[h] = 0.f;
#pragma unroll
    for (int s = 0; s < SAMP; ++s) {
      const _Float16* hn = H1 + (size_t)neigh2[b * SAMP + s] * HID;
#pragma unroll
      for (int q = 0; q < 4; ++q) {
        f16x8 v = *(const f16x8*)(hn + q * 8);
#pragma unroll
        for (int j = 0; j < 8; ++j) na[q * 8 + j] += (float)v[j];
      }
    }
#pragma unroll
    for (int h = 0; h < HID; ++h) comb[HID + h] = 0.2f * na[h];
  }

  float h2[HID];
#pragma unroll 4
  for (int h = 0; h < HID; ++h) {
    float a = 0.f;
#pragma unroll
    for (int k = 0; k < 2 * HID; ++k) a += comb[k] * W2[h * 2 * HID + k];
    h2[h] = a > 0.f ? a : 0.f;
  }

  float* ob = out + (size_t)b * NCLS;
#pragma unroll 4
  for (int c = 0; c < NCLS; ++c) {
    float a = 0.f;
#pragma unroll
    for (int k = 0; k < HID; ++k) a += h2[k] * Wc[c * HID + k];
    ob[c] = a;
  }
}

extern "C" void kernel_launch(void* const* d_in, const int* in_sizes, int n_in,
                              void* d_out, int out_size, void* d_ws, size_t ws_size,
                              hipStream_t stream) {
  const float* feat   = (const float*)d_in[0];
  const float* W1     = (const float*)d_in[1];
  const float* W2     = (const float*)d_in[2];
  const float* Wc     = (const float*)d_in[3];
  const int*   nodes  = (const int*)d_in[4];
  const int*   neigh1 = (const int*)d_in[5];
  const int*   neigh2 = (const int*)d_in[6];
  float* out = (float*)d_out;

  const int M = in_sizes[0] / NFEAT;   // 100000 nodes
  const int B = in_sizes[4];           // 16384 batch

  // workspace: Bfrag f16 [32*64*4*4] (64 KB), PQ f16 [M][64], H1 f16 [M][32]
  size_t bfrag_elems = (size_t)KSTEPS * 64 * 4 * 4;
  size_t need = (bfrag_elems + (size_t)M * NPQ + (size_t)M * HID) * sizeof(_Float16);
  if (ws_size < need) return;  // fail loudly (output stays poisoned)

  _Float16* Bfrag = (_Float16*)d_ws;
  _Float16* PQ = Bfrag + bfrag_elems;
  _Float16* H1 = PQ + (size_t)M * NPQ;

  k0_bfrag<<<(KSTEPS * 64 * 4 + 255) / 256, 256, 0, stream>>>(W1, Bfrag);
  k1_mfma<<<(M + 127) / 128, 256, 0, stream>>>(feat, Bfrag, PQ, M);
  k2_agg<<<(M * 4 + 255) / 256, 256, 0, stream>>>(PQ, neigh1, H1, M);
  k3_layer2<<<(B + 63) / 64, 64, 0, stream>>>(H1, W2, Wc, nodes, neigh2, out, B);
}